// Round 3
// baseline (196.106 us; speedup 1.0000x reference)
//
#include <hip/hip_runtime.h>
#include <hip/hip_bf16.h>

// B=2, M=2048, HID=1024, NH=16, D=64.  Key identity: no softmax in the
// reference, so out = ((h Wq^T)(h Wk^T)^T (h Wv^T)) Wo^T reassociates to
// per-head  O_h = Q_h (K_h^T V_h)  with K^T V only 64x64 per head.
//
// Dtypes (round-2 post-mortem): inputs fp32, d_out fp32 (reference output
// dtype is fp32; the "bf16" in the test label is the comparison policy —
// np ref is bf16-rounded, hence round-0's exact 584.0).  Round-2's 774
// absmax = bf16 u16 pairs misread as fp32.  Internal compute bf16/fp32.
//
// Pipeline:
//   0. prep: downcast h->hb, Wq|Wk|Wv->wcat, Wo->wob (bf16); zero S
//   1. QKVb = hb @ wcat^T        (4096x3072 bf16)          [MFMA GEMM]
//   2. S[b,h] = K_h^T V_h        (32 x 64x64 fp32, atomic) [VALU]
//   3. O = Q_h @ S[b,h]          (4096x1024 bf16, overlays hb) [VALU]
//   4. out = O @ wob^T           (4096x1024 fp32 -> d_out) [MFMA GEMM]

typedef unsigned short u16;
typedef unsigned int u32;
typedef __attribute__((ext_vector_type(8))) short bf16x8;
typedef __attribute__((ext_vector_type(4))) float f32x4;

__device__ __forceinline__ void async_copy16(void* lds, const void* g) {
  __builtin_amdgcn_global_load_lds((const __attribute__((address_space(1))) void*)g,
                                   (__attribute__((address_space(3))) void*)lds,
                                   16, 0, 0);
}

__device__ __forceinline__ u16 f2bf(float f) {
  union { __hip_bfloat16 h; u16 u; } c;
  c.h = __float2bfloat16(f);
  return c.u;
}
__device__ __forceinline__ float bflo(u32 w) {
  union { u32 u; float f; } c; c.u = w << 16; return c.f;
}
__device__ __forceinline__ float bfhi(u32 w) {
  union { u32 u; float f; } c; c.u = w & 0xFFFF0000u; return c.f;
}
__device__ __forceinline__ ushort4 cvt4(float4 v) {
  ushort4 o; o.x = f2bf(v.x); o.y = f2bf(v.y); o.z = f2bf(v.z); o.w = f2bf(v.w);
  return o;
}

// ---------------------------------------------------------------- prep ------
// Downcast all fp32 operands to bf16 and zero S.  All region boundaries are
// multiples of 256 float4s, so branches are block-uniform.
__global__ __launch_bounds__(256) void prep(const float4* __restrict__ h,
                                            const float4* __restrict__ wq,
                                            const float4* __restrict__ wk,
                                            const float4* __restrict__ wv,
                                            const float4* __restrict__ wo,
                                            ushort4* __restrict__ hb,
                                            ushort4* __restrict__ wcat,
                                            ushort4* __restrict__ wob,
                                            float4* __restrict__ S) {
  int i = blockIdx.x * 256 + threadIdx.x;  // float4 units
  if (i < 1048576) { hb[i] = cvt4(h[i]); return; }          // h: 4096x1024
  i -= 1048576;
  if (i < 262144) { wcat[i] = cvt4(wq[i]); return; }        // Wq -> rows 0..1023
  i -= 262144;
  if (i < 262144) { wcat[262144 + i] = cvt4(wk[i]); return; }
  i -= 262144;
  if (i < 262144) { wcat[524288 + i] = cvt4(wv[i]); return; }
  i -= 262144;
  if (i < 262144) { wob[i] = cvt4(wo[i]); return; }
  i -= 262144;
  S[i] = float4{0.f, 0.f, 0.f, 0.f};                        // 32*64*64 fp32
}

// ------------------------------------------------------------- NT GEMM ------
// C[m,n] = sum_k A[m*K+k] * B[n*K+k].  A,B bf16 row-major.
// 128x128 tile, BK=32, 4 waves (2x2), each wave 64x64 via 4x4 of 16x16x32 MFMA.
template <bool BF16_OUT>
__global__ __launch_bounds__(256) void gemm_bt(const u16* __restrict__ A,
                                               const u16* __restrict__ B,
                                               void* __restrict__ Cv,
                                               int M, int N, int K) {
  __shared__ u16 Als[128 * 32];
  __shared__ u16 Bls[128 * 32];
  const int t = threadIdx.x;
  const int lane = t & 63;
  const int wave = t >> 6;
  const int wm = (wave >> 1) * 64;
  const int wn = (wave & 1) * 64;
  const int lrow = lane & 15;      // MFMA m/n index
  const int lk = (lane >> 4) * 8;  // MFMA k offset (quad*8)
  const int m0 = blockIdx.y * 128;
  const int n0 = blockIdx.x * 128;

  // staging: LDS tile row-major [128][32] bf16; thread t covers 16 B at t*16.
  const int srow = t >> 2;
  const int scol = (t & 3) * 8;
  const u16* Ag0 = A + (size_t)(m0 + srow) * K + scol;
  const u16* Bg0 = B + (size_t)(n0 + srow) * K + scol;
  u16* Al0 = Als + t * 8;
  u16* Bl0 = Bls + t * 8;

  f32x4 acc[4][4];
#pragma unroll
  for (int i = 0; i < 4; ++i)
#pragma unroll
    for (int j = 0; j < 4; ++j) acc[i][j] = {0.f, 0.f, 0.f, 0.f};

  for (int k0 = 0; k0 < K; k0 += 32) {
    async_copy16(Al0,        Ag0 + k0);
    async_copy16(Al0 + 2048, Ag0 + (size_t)64 * K + k0);
    async_copy16(Bl0,        Bg0 + k0);
    async_copy16(Bl0 + 2048, Bg0 + (size_t)64 * K + k0);
    __syncthreads();

    bf16x8 af[4], bfv[4];
#pragma unroll
    for (int i = 0; i < 4; ++i) {
      af[i]  = *(const bf16x8*)(Als + (wm + i * 16 + lrow) * 32 + lk);
      bfv[i] = *(const bf16x8*)(Bls + (wn + i * 16 + lrow) * 32 + lk);
    }
#pragma unroll
    for (int mi = 0; mi < 4; ++mi)
#pragma unroll
      for (int ni = 0; ni < 4; ++ni)
        acc[mi][ni] = __builtin_amdgcn_mfma_f32_16x16x32_bf16(
            af[mi], bfv[ni], acc[mi][ni], 0, 0, 0);
    __syncthreads();
  }

  // C/D layout (verified m89/m91): col = lane&15, row = (lane>>4)*4 + r
  const int crow0 = m0 + wm + (lane >> 4) * 4;
  const int ccol0 = n0 + wn + (lane & 15);
#pragma unroll
  for (int mi = 0; mi < 4; ++mi)
#pragma unroll
    for (int ni = 0; ni < 4; ++ni) {
      const int col = ccol0 + ni * 16;
#pragma unroll
      for (int r = 0; r < 4; ++r) {
        const size_t idx = (size_t)(crow0 + mi * 16 + r) * N + col;
        if (BF16_OUT) ((u16*)Cv)[idx]   = f2bf(acc[mi][ni][r]);
        else          ((float*)Cv)[idx] = acc[mi][ni][r];
      }
    }
}

// ------------------------------------------------------- S = K^T V ----------
// QKVb: (4096, 3072) bf16; cols [0,1024)=Q [1024,2048)=K [2048,3072)=V.
// grid (32 bh, 8 chunks of 256 rows); atomicAdd into S (32 x 64 x 64 fp32).
__global__ __launch_bounds__(256) void s_kernel(const u16* __restrict__ QKV,
                                                float* __restrict__ S) {
  const int bh = blockIdx.x;
  const int b = bh >> 4, hh = bh & 15;
  const int row0 = b * 2048 + blockIdx.y * 256;
  const u16* Kg = QKV + (size_t)row0 * 3072 + 1024 + hh * 64;

  __shared__ float Ks[8][64];
  __shared__ float Vs[8][64];
  const int t = threadIdx.x;
  const int lr = t >> 5;        // 0..7
  const int lc = (t & 31) * 2;  // 0..62
  const int d1 = (t >> 4) * 4;
  const int d2 = (t & 15) * 4;

  float acc[4][4];
#pragma unroll
  for (int i = 0; i < 4; ++i)
#pragma unroll
    for (int j = 0; j < 4; ++j) acc[i][j] = 0.f;

  for (int r0 = 0; r0 < 256; r0 += 8) {
    __syncthreads();
    const u16* kp = Kg + (size_t)(r0 + lr) * 3072 + lc;
    const u32 kw = *(const u32*)kp;
    const u32 vw = *(const u32*)(kp + 1024);  // V is K + 1024 cols
    Ks[lr][lc] = bflo(kw); Ks[lr][lc + 1] = bfhi(kw);
    Vs[lr][lc] = bflo(vw); Vs[lr][lc + 1] = bfhi(vw);
    __syncthreads();
#pragma unroll
    for (int r = 0; r < 8; ++r) {
      float kv[4], vv[4];
      *(float4*)kv = *(const float4*)&Ks[r][d1];
      *(float4*)vv = *(const float4*)&Vs[r][d2];
#pragma unroll
      for (int i = 0; i < 4; ++i)
#pragma unroll
        for (int j = 0; j < 4; ++j) acc[i][j] += kv[i] * vv[j];
    }
  }
  float* Sp = S + (size_t)bh * 4096;
#pragma unroll
  for (int i = 0; i < 4; ++i)
#pragma unroll
    for (int j = 0; j < 4; ++j)
      atomicAdd(&Sp[(d1 + i) * 64 + d2 + j], acc[i][j]);
}

// ------------------------------------------------------- O = Q @ S ----------
// grid (16 heads, 64 row-blocks of 64). Writes O as bf16 (4096 x 1024).
__global__ __launch_bounds__(256) void o_kernel(const u16* __restrict__ QKV,
                                                const float* __restrict__ S,
                                                u16* __restrict__ Ob) {
  const int hh = blockIdx.x;
  const int rb = blockIdx.y;
  const int b = rb >> 5;
  const int row0 = rb * 64;

  __shared__ float Qs[64][68];  // +4 pad: float4-aligned, breaks conflicts
  __shared__ float Ss[64][68];
  const int t = threadIdx.x;
  {
    const int r = t >> 2;
    const int c0 = (t & 3) * 16;
    const u16* qp = QKV + (size_t)(row0 + r) * 3072 + hh * 64 + c0;
#pragma unroll
    for (int half = 0; half < 2; ++half) {
      const uint4 w = *(const uint4*)(qp + half * 8);
      float* dst = &Qs[r][c0 + half * 8];
      dst[0] = bflo(w.x); dst[1] = bfhi(w.x);
      dst[2] = bflo(w.y); dst[3] = bfhi(w.y);
      dst[4] = bflo(w.z); dst[5] = bfhi(w.z);
      dst[6] = bflo(w.w); dst[7] = bfhi(w.w);
    }
    const float* sp = S + (size_t)(b * 16 + hh) * 4096 + r * 64 + c0;
#pragma unroll
    for (int i = 0; i < 4; ++i)
      *(float4*)&Ss[r][c0 + i * 4] = *(const float4*)(sp + i * 4);
  }
  __syncthreads();

  const int tr = (t >> 4) * 4;
  const int tc = (t & 15) * 4;
  float acc[4][4];
#pragma unroll
  for (int i = 0; i < 4; ++i)
#pragma unroll
    for (int j = 0; j < 4; ++j) acc[i][j] = 0.f;

  for (int k = 0; k < 64; ++k) {
    float q[4], s[4];
#pragma unroll
    for (int i = 0; i < 4; ++i) q[i] = Qs[tr + i][k];
    *(float4*)s = *(const float4*)&Ss[k][tc];
#pragma unroll
    for (int i = 0; i < 4; ++i)
#pragma unroll
      for (int j = 0; j < 4; ++j) acc[i][j] += q[i] * s[j];
  }

#pragma unroll
  for (int i = 0; i < 4; ++i) {
    ushort4 o;
    o.x = f2bf(acc[i][0]); o.y = f2bf(acc[i][1]);
    o.z = f2bf(acc[i][2]); o.w = f2bf(acc[i][3]);
    *(ushort4*)&Ob[(size_t)(row0 + tr + i) * 1024 + hh * 64 + tc] = o;
  }
}

// ---------------------------------------------------------------------------
extern "C" void kernel_launch(void* const* d_in, const int* in_sizes, int n_in,
                              void* d_out, int out_size, void* d_ws, size_t ws_size,
                              hipStream_t stream) {
  const float* h  = (const float*)d_in[0];  // (4096, 1024) fp32
  // d_in[1] = key_pe: dead branch in reference, unused.
  const float* Wq = (const float*)d_in[2];
  const float* Wk = (const float*)d_in[3];
  const float* Wv = (const float*)d_in[4];
  const float* Wo = (const float*)d_in[5];

  char* ws = (char*)d_ws;
  u16*   hb   = (u16*)(ws);                    // 4096*1024*2 = 8 MiB @ 0
  u16*   Ob   = (u16*)(ws);                    // overlays hb (dead after GEMM-1)
  u16*   wcat = (u16*)(ws + (8ull  << 20));    // 3072*1024*2 = 6 MiB
  u16*   wob  = (u16*)(ws + (14ull << 20));    // 1024*1024*2 = 2 MiB
  u16*   QKVb = (u16*)(ws + (16ull << 20));    // 4096*3072*2 = 24 MiB
  float* S    = (float*)(ws + (40ull << 20));  // 32*64*64*4  = 0.5 MiB
  // total ws use: 40.5 MiB

  prep<<<8320, 256, 0, stream>>>((const float4*)h, (const float4*)Wq,
                                 (const float4*)Wk, (const float4*)Wv,
                                 (const float4*)Wo, (ushort4*)hb,
                                 (ushort4*)wcat, (ushort4*)wob, (float4*)S);
  gemm_bt<true><<<dim3(24, 32), 256, 0, stream>>>(hb, wcat, QKVb, 4096, 3072, 1024);
  s_kernel<<<dim3(32, 8), 256, 0, stream>>>(QKVb, S);
  o_kernel<<<dim3(16, 64), 256, 0, stream>>>(QKVb, S, Ob);
  gemm_bt<false><<<dim3(8, 32), 256, 0, stream>>>(Ob, wob, d_out, 4096, 1024, 1024);
}

// Round 4
// 194.908 us; speedup vs baseline: 1.0061x; 1.0061x over previous
//
#include <hip/hip_runtime.h>
#include <hip/hip_bf16.h>

// B=2, M=2048, HID=1024, NH=16, D=64.  No softmax in the reference, so
//   out = ((h Wq^T)(h Wk^T)^T (h Wv^T)) Wo^T
// reassociates twice:  S_{b,h} = K_h^T V_h  (64x64), and
//   out_b = Q_b @ T_b   with  T_b[h*64+d, n] = sum_j S_{b,h}[d,j] Wo[n, h*64+j]
// (heads concatenate, so the per-head right-folds stack into one 1024x1024 T).
//
// Dtypes: inputs fp32, d_out fp32; internal bf16 with fp32 accumulate
// (round-3: absmax 4.0 vs threshold 11.68).
//
// Pipeline:
//   0. prep: h->hb (bf16), Wq|Wk|Wv->wcat (bf16); zero S
//   1. QKVb = hb @ wcat^T        (4096x3072 bf16)            [MFMA GEMM]
//   2. S[b,h] = K_h^T V_h        (32 x 64x64 fp32, atomic)   [VALU]
//   3. Tt[b][n,k] = (S_h Wo_h^T)^T  (2 x 1024x1024 bf16)     [VALU, fp32 in]
//   4. out = Q @ Tt_b^T          (4096x1024 fp32 -> d_out)   [MFMA GEMM]

typedef unsigned short u16;
typedef unsigned int u32;
typedef __attribute__((ext_vector_type(8))) short bf16x8;
typedef __attribute__((ext_vector_type(4))) float f32x4;

__device__ __forceinline__ void async_copy16(void* lds, const void* g) {
  __builtin_amdgcn_global_load_lds((const __attribute__((address_space(1))) void*)g,
                                   (__attribute__((address_space(3))) void*)lds,
                                   16, 0, 0);
}

__device__ __forceinline__ u16 f2bf(float f) {
  union { __hip_bfloat16 h; u16 u; } c;
  c.h = __float2bfloat16(f);
  return c.u;
}
__device__ __forceinline__ float bflo(u32 w) {
  union { u32 u; float f; } c; c.u = w << 16; return c.f;
}
__device__ __forceinline__ float bfhi(u32 w) {
  union { u32 u; float f; } c; c.u = w & 0xFFFF0000u; return c.f;
}
__device__ __forceinline__ ushort4 cvt4(float4 v) {
  ushort4 o; o.x = f2bf(v.x); o.y = f2bf(v.y); o.z = f2bf(v.z); o.w = f2bf(v.w);
  return o;
}

// ---------------------------------------------------------------- prep ------
// h->hb, Wq|Wk|Wv->wcat (bf16); zero S.  Region bounds are multiples of 256
// float4s -> block-uniform branches.
__global__ __launch_bounds__(256) void prep(const float4* __restrict__ h,
                                            const float4* __restrict__ wq,
                                            const float4* __restrict__ wk,
                                            const float4* __restrict__ wv,
                                            ushort4* __restrict__ hb,
                                            ushort4* __restrict__ wcat,
                                            float4* __restrict__ S) {
  int i = blockIdx.x * 256 + threadIdx.x;  // float4 units
  if (i < 1048576) { hb[i] = cvt4(h[i]); return; }          // h: 4096x1024
  i -= 1048576;
  if (i < 262144) { wcat[i] = cvt4(wq[i]); return; }
  i -= 262144;
  if (i < 262144) { wcat[262144 + i] = cvt4(wk[i]); return; }
  i -= 262144;
  if (i < 262144) { wcat[524288 + i] = cvt4(wv[i]); return; }
  i -= 262144;
  S[i] = float4{0.f, 0.f, 0.f, 0.f};                        // 32*64*64 fp32
}

// ------------------------------------------------------------- NT GEMM ------
// C[m,n] = sum_k A[m*lda+k] * B[n*K+k].  A,B bf16.  128x128 tile, BK=32,
// 4 waves (2x2), each wave 64x64 via 4x4 of 16x16x32 MFMA.
// If B1 != nullptr, row-blocks with m0 >= 2048 use B1 (per-batch T).
template <bool BF16_OUT>
__global__ __launch_bounds__(256) void gemm_bt(const u16* __restrict__ A, int lda,
                                               const u16* __restrict__ B0,
                                               const u16* __restrict__ B1,
                                               void* __restrict__ Cv,
                                               int N, int K) {
  __shared__ u16 Als[128 * 32];
  __shared__ u16 Bls[128 * 32];
  const int t = threadIdx.x;
  const int lane = t & 63;
  const int wave = t >> 6;
  const int wm = (wave >> 1) * 64;
  const int wn = (wave & 1) * 64;
  const int lrow = lane & 15;      // MFMA m/n index
  const int lk = (lane >> 4) * 8;  // MFMA k offset (quad*8)
  const int m0 = blockIdx.y * 128;
  const int n0 = blockIdx.x * 128;
  const u16* B = (B1 != nullptr && m0 >= 2048) ? B1 : B0;

  // staging: LDS tile row-major [128][32] bf16; thread t covers 16 B at t*16
  // (wave-uniform base + lane*16 -> legal global_load_lds dest).
  const int srow = t >> 2;
  const int scol = (t & 3) * 8;
  const u16* Ag0 = A + (size_t)(m0 + srow) * lda + scol;
  const u16* Bg0 = B + (size_t)(n0 + srow) * K + scol;
  u16* Al0 = Als + t * 8;
  u16* Bl0 = Bls + t * 8;

  f32x4 acc[4][4];
#pragma unroll
  for (int i = 0; i < 4; ++i)
#pragma unroll
    for (int j = 0; j < 4; ++j) acc[i][j] = {0.f, 0.f, 0.f, 0.f};

  for (int k0 = 0; k0 < K; k0 += 32) {
    async_copy16(Al0,        Ag0 + k0);
    async_copy16(Al0 + 2048, Ag0 + (size_t)64 * lda + k0);
    async_copy16(Bl0,        Bg0 + k0);
    async_copy16(Bl0 + 2048, Bg0 + (size_t)64 * K + k0);
    __syncthreads();

    bf16x8 af[4], bfv[4];
#pragma unroll
    for (int i = 0; i < 4; ++i) {
      af[i]  = *(const bf16x8*)(Als + (wm + i * 16 + lrow) * 32 + lk);
      bfv[i] = *(const bf16x8*)(Bls + (wn + i * 16 + lrow) * 32 + lk);
    }
#pragma unroll
    for (int mi = 0; mi < 4; ++mi)
#pragma unroll
      for (int ni = 0; ni < 4; ++ni)
        acc[mi][ni] = __builtin_amdgcn_mfma_f32_16x16x32_bf16(
            af[mi], bfv[ni], acc[mi][ni], 0, 0, 0);
    __syncthreads();
  }

  // C/D layout (verified m89/m91): col = lane&15, row = (lane>>4)*4 + r
  const int crow0 = m0 + wm + (lane >> 4) * 4;
  const int ccol0 = n0 + wn + (lane & 15);
#pragma unroll
  for (int mi = 0; mi < 4; ++mi)
#pragma unroll
    for (int ni = 0; ni < 4; ++ni) {
      const int col = ccol0 + ni * 16;
#pragma unroll
      for (int r = 0; r < 4; ++r) {
        const size_t idx = (size_t)(crow0 + mi * 16 + r) * N + col;
        if (BF16_OUT) ((u16*)Cv)[idx]   = f2bf(acc[mi][ni][r]);
        else          ((float*)Cv)[idx] = acc[mi][ni][r];
      }
    }
}

// ------------------------------------------------------- S = K^T V ----------
// QKVb: (4096, 3072) bf16; cols [0,1024)=Q [1024,2048)=K [2048,3072)=V.
// grid (32 bh, 16 chunks of 128 rows); 32-row LDS stages, uint4 loads;
// atomicAdd into S (32 x 64 x 64 fp32).
__global__ __launch_bounds__(256) void s_kernel(const u16* __restrict__ QKV,
                                                float* __restrict__ S) {
  const int bh = blockIdx.x;
  const int b = bh >> 4, hh = bh & 15;
  const int row0 = b * 2048 + blockIdx.y * 128;
  const u16* Kg = QKV + (size_t)row0 * 3072 + 1024 + hh * 64;

  __shared__ float Ks[32][64];
  __shared__ float Vs[32][64];
  const int t = threadIdx.x;
  const int lr = t >> 3;        // 0..31
  const int lc = (t & 7) * 8;   // 0..56
  const int d1 = (t >> 4) * 4;
  const int d2 = (t & 15) * 4;

  float acc[4][4] = {};

  for (int r0 = 0; r0 < 128; r0 += 32) {
    const u16* kp = Kg + (size_t)(r0 + lr) * 3072 + lc;
    const uint4 kw = *(const uint4*)kp;
    const uint4 vw = *(const uint4*)(kp + 1024);  // V = K + 1024 cols
    __syncthreads();  // prev-iter readers done
    float* kd = &Ks[lr][lc];
    *(float4*)(kd)     = float4{bflo(kw.x), bfhi(kw.x), bflo(kw.y), bfhi(kw.y)};
    *(float4*)(kd + 4) = float4{bflo(kw.z), bfhi(kw.z), bflo(kw.w), bfhi(kw.w)};
    float* vd = &Vs[lr][lc];
    *(float4*)(vd)     = float4{bflo(vw.x), bfhi(vw.x), bflo(vw.y), bfhi(vw.y)};
    *(float4*)(vd + 4) = float4{bflo(vw.z), bfhi(vw.z), bflo(vw.w), bfhi(vw.w)};
    __syncthreads();
#pragma unroll
    for (int r = 0; r < 32; ++r) {
      float kv[4], vv[4];
      *(float4*)kv = *(const float4*)&Ks[r][d1];
      *(float4*)vv = *(const float4*)&Vs[r][d2];
#pragma unroll
      for (int i = 0; i < 4; ++i)
#pragma unroll
        for (int j = 0; j < 4; ++j) acc[i][j] += kv[i] * vv[j];
    }
  }
  float* Sp = S + (size_t)bh * 4096;
#pragma unroll
  for (int i = 0; i < 4; ++i)
#pragma unroll
    for (int j = 0; j < 4; ++j)
      atomicAdd(&Sp[(d1 + i) * 64 + d2 + j], acc[i][j]);
}

// ------------------------------------------- Tt = (S_h Wo_h^T)^T ------------
// T_b[h*64+d, n] = sum_j S_{b,h}[d,j] * Wo[n, h*64+j];  stored transposed
// (row n, col h*64+d) bf16 so the final GEMM can consume it NT-style.
// grid (8 n-chunks, 16 heads, 2 batches); S and Wo read as fp32.
__global__ __launch_bounds__(256) void t_kernel(const float* __restrict__ S,
                                                const float* __restrict__ Wo,
                                                u16* __restrict__ Tt) {
  const int n0 = blockIdx.x * 128;
  const int hh = blockIdx.y;
  const int b  = blockIdx.z;
  __shared__ float Ss[64][68];    // pad 68: td-group reads land 2-way (free)
  __shared__ float Ws[128][68];
  const int t = threadIdx.x;
  {
    const float* sg = S + (size_t)(b * 16 + hh) * 4096 + (t >> 2) * 64 + (t & 3) * 16;
    float* sd = &Ss[t >> 2][(t & 3) * 16];
#pragma unroll
    for (int i = 0; i < 4; ++i) *(float4*)(sd + 4 * i) = *(const float4*)(sg + 4 * i);
    const float* wg = Wo + (size_t)(n0 + (t >> 1)) * 1024 + hh * 64 + (t & 1) * 32;
    float* wd = &Ws[t >> 1][(t & 1) * 32];
#pragma unroll
    for (int i = 0; i < 8; ++i) *(float4*)(wd + 4 * i) = *(const float4*)(wg + 4 * i);
  }
  __syncthreads();

  const int td = (t >> 4) * 4;  // d = td..td+3
  const int tn = t & 15;        // n = n0 + tn + 16k
  float acc[4][8] = {};
  for (int jj = 0; jj < 64; jj += 4) {
    float4 sv[4], wv[8];
#pragma unroll
    for (int i = 0; i < 4; ++i) sv[i] = *(const float4*)&Ss[td + i][jj];
#pragma unroll
    for (int k = 0; k < 8; ++k) wv[k] = *(const float4*)&Ws[tn + 16 * k][jj];
#pragma unroll
    for (int i = 0; i < 4; ++i)
#pragma unroll
      for (int k = 0; k < 8; ++k)
        acc[i][k] += sv[i].x * wv[k].x + sv[i].y * wv[k].y +
                     sv[i].z * wv[k].z + sv[i].w * wv[k].w;
  }

  u16* tp = Tt + (size_t)b * 1048576;
#pragma unroll
  for (int k = 0; k < 8; ++k) {
    const int n = n0 + tn + 16 * k;
    ushort4 o;
    o.x = f2bf(acc[0][k]); o.y = f2bf(acc[1][k]);
    o.z = f2bf(acc[2][k]); o.w = f2bf(acc[3][k]);
    *(ushort4*)&tp[(size_t)n * 1024 + hh * 64 + td] = o;
  }
}

// ---------------------------------------------------------------------------
extern "C" void kernel_launch(void* const* d_in, const int* in_sizes, int n_in,
                              void* d_out, int out_size, void* d_ws, size_t ws_size,
                              hipStream_t stream) {
  const float* h  = (const float*)d_in[0];  // (4096, 1024) fp32
  // d_in[1] = key_pe: dead branch in reference, unused.
  const float* Wq = (const float*)d_in[2];
  const float* Wk = (const float*)d_in[3];
  const float* Wv = (const float*)d_in[4];
  const float* Wo = (const float*)d_in[5];

  char* ws = (char*)d_ws;
  u16*   hb   = (u16*)(ws);                    // 4096*1024*2 = 8 MiB @ 0
  u16*   wcat = (u16*)(ws + (8ull  << 20));    // 3072*1024*2 = 6 MiB
  u16*   QKVb = (u16*)(ws + (16ull << 20));    // 4096*3072*2 = 24 MiB
  float* S    = (float*)(ws + (40ull << 20));  // 32*64*64*4  = 0.5 MiB
  u16*   Tt   = (u16*)(ws + (41ull << 20));    // 2*1024*1024*2 = 4 MiB
  // total ws use: 45 MiB (ws_size = 256 MiB per round-3 fill WRITE_SIZE)

  prep<<<7200, 256, 0, stream>>>((const float4*)h, (const float4*)Wq,
                                 (const float4*)Wk, (const float4*)Wv,
                                 (ushort4*)hb, (ushort4*)wcat, (float4*)S);
  gemm_bt<true><<<dim3(24, 32), 256, 0, stream>>>(hb, 1024, wcat, nullptr,
                                                  QKVb, 3072, 1024);
  s_kernel<<<dim3(32, 16), 256, 0, stream>>>(QKVb, S);
  t_kernel<<<dim3(8, 16, 2), 256, 0, stream>>>(S, Wo, Tt);
  gemm_bt<false><<<dim3(8, 32), 256, 0, stream>>>(QKVb, 3072, Tt, Tt + 1048576,
                                                  d_out, 1024, 1024);
}